// Round 5
// baseline (2485.671 us; speedup 1.0000x reference)
//
#include <hip/hip_runtime.h>

#define N_NODES 1000000
#define D 64
#define H 128

typedef float f4 __attribute__((ext_vector_type(4)));
typedef float v2f __attribute__((ext_vector_type(2)));
typedef _Float16 h8 __attribute__((ext_vector_type(8)));

// ---------------------------------------------------------------------------
// Detect whether edge_index arrived as int32 or int64 (indices < 2^20, so for
// int64 every odd u32 word is zero). flag = 1 -> int32, 0 -> int64.
// ---------------------------------------------------------------------------
__global__ __launch_bounds__(256) void detect_kernel(const unsigned int* __restrict__ e,
                                                     int* __restrict__ flag) {
    __shared__ int any_nz;
    if (threadIdx.x == 0) any_nz = 0;
    __syncthreads();
    int nz = 0;
    for (int k = threadIdx.x; k < 2048; k += 256) {
        if (e[2 * k + 1] != 0u) nz = 1;
    }
    if (nz) atomicOr(&any_nz, 1);
    __syncthreads();
    if (threadIdx.x == 0) *flag = any_nz;
}

// ---------------------------------------------------------------------------
// One-time transpose of w2 [D][H] -> w2t [H][D]: contiguous per-hidden-unit
// rows for the scalar pipe (worth 1140->785 us in round 1).
// ---------------------------------------------------------------------------
__global__ __launch_bounds__(256) void transpose_w2_kernel(const float* __restrict__ w2,
                                                           float* __restrict__ w2t) {
    int idx = blockIdx.x * 256 + threadIdx.x;  // D*H = 8192 elements
    if (idx < D * H) {
        int i = idx >> 7;        // row in w2  (output dim)
        int j = idx & (H - 1);   // col in w2  (hidden dim)
        w2t[j * D + i] = w2[idx];
    }
}

// ---------------------------------------------------------------------------
// Scatter-add with PACKED f32x2 atomics: 32 lanes per edge, each lane owns a
// float2 feature pair. Halves the atomic-op count 80M -> 40M (the scatter is
// atomic-throughput-bound, not BW-bound: ~850 MB traffic = 135 us floor vs
// ~620 us measured). Falls back to 2x dword atomicAdd if the builtin is
// unavailable (compile-safe).
// ---------------------------------------------------------------------------
__global__ __launch_bounds__(256) void scatter_kernel(const void* __restrict__ edges,
                                                      const float* __restrict__ emb,
                                                      float* __restrict__ msg,
                                                      const int* __restrict__ flag,
                                                      int E) {
    long long t = (long long)blockIdx.x * 256 + threadIdx.x;
    int e  = (int)(t >> 5);   // edge index
    int pr = (int)(t & 31);   // feature-pair index (2 floats each)
    if (e >= E) return;

    long long s, d;
    if (*flag) {  // int32 layout
        const int* p = (const int*)edges;
        s = p[e];
        d = p[E + e];
    } else {      // int64 layout
        const long long* p = (const long long*)edges;
        s = p[e];
        d = p[E + e];
    }

    v2f v = *((const v2f*)(emb + s * (long long)D) + pr);
    float* dp = msg + d * (long long)D + pr * 2;

#if __has_builtin(__builtin_amdgcn_global_atomic_fadd_v2f32)
    typedef v2f __attribute__((address_space(1)))* gv2f;
    __builtin_amdgcn_global_atomic_fadd_v2f32((gv2f)(v2f*)dp, v);
#else
    atomicAdd(dp, v[0]);
    atomicAdd(dp + 1, v[1]);
#endif
}

// ---------------------------------------------------------------------------
// MLP layer 1: h[n][j] = relu(b1[j] + sum_k msg[n][k] * w1[j][k]), j=0..127.
// One thread per node; h is written as fp16 IN PLACE over the fp32 msg row
// (128 x fp16 = 256 B = the exact row footprint). Live state: m[16 f4] = 64
// floats + an 8-wide h buffer -> ~80 VGPRs, no u[] co-resident. Rounds 2-4
// proved attributes can't force the allocator past ~72-88 regs when both
// m and u are live; this split removes the need.
// fp16 h precision: |h| <~ 8, rel err 2^-11 -> ~0.004 absmax added.
// ---------------------------------------------------------------------------
__global__ __launch_bounds__(256)
__attribute__((amdgpu_waves_per_eu(5, 5)))
void hidden_kernel(float* __restrict__ io,
                   const float* __restrict__ w1,
                   const float* __restrict__ b1) {
    int n = blockIdx.x * 256 + threadIdx.x;
    if (n >= N_NODES) return;

    const f4* __restrict__ mp = (const f4*)(io + (size_t)n * D);
    f4 m[D / 4];
#pragma unroll
    for (int c = 0; c < D / 4; ++c) m[c] = mp[c];

    h8* __restrict__ hp = (h8*)(io + (size_t)n * D);

#pragma unroll 2
    for (int jb = 0; jb < H / 8; ++jb) {
        h8 hv;
#pragma unroll
        for (int t = 0; t < 8; ++t) {
            int j = jb * 8 + t;
            const f4* __restrict__ wr = (const f4*)(w1 + j * D);
            f4 acc = (f4){0.0f, 0.0f, 0.0f, 0.0f};
#pragma unroll
            for (int c = 0; c < D / 4; ++c) acc = m[c] * wr[c] + acc;
            float h = (acc[0] + acc[1]) + (acc[2] + acc[3]) + b1[j];
            hv[t] = (_Float16)fmaxf(h, 0.0f);
        }
        hp[jb] = hv;  // all m loads precede these stores (same-row data dep)
    }
}

// ---------------------------------------------------------------------------
// MLP layer 2 + residual: u[n][i] = relu(b2[i] + sum_j h[n][j] * w2t[j][i]),
// out[n] = emb[n] + u. TWO threads per node, one per 32-output half, so the
// live set is u[8 f4] = 32 floats + h window -> ~50 VGPRs, spill-impossible
// at any occupancy. Halves are WAVE-aligned (wave w: half = w&1, node =
// (w>>1)*64 + lane) so w2t row addresses stay wave-uniform (scalar s_loads).
// The two threads of a node share the fp16 h row that the final store
// overwrites -> __syncthreads() between last h read and first store.
// ---------------------------------------------------------------------------
__global__ __launch_bounds__(256) void out_kernel(float* __restrict__ io,
                                                  const float* __restrict__ emb,
                                                  const float* __restrict__ w2t,
                                                  const float* __restrict__ b2) {
    int tid  = blockIdx.x * 256 + threadIdx.x;
    int wave = tid >> 6;
    int lane = tid & 63;
    int half = wave & 1;                 // which 32 outputs
    int n    = (wave >> 1) * 64 + lane;  // node
    bool active = (n < N_NODES);

    f4 u[8];

    if (active) {
        const f4* __restrict__ b2v = (const f4*)(b2 + half * 32);
#pragma unroll
        for (int c = 0; c < 8; ++c) u[c] = b2v[c];

        const h8* __restrict__ hp = (const h8*)(io + (size_t)n * D);
#pragma unroll 2
        for (int jb = 0; jb < H / 8; ++jb) {
            h8 hv = hp[jb];
#pragma unroll
            for (int t = 0; t < 8; ++t) {
                float h = (float)hv[t];
                const f4* __restrict__ wc =
                    (const f4*)(w2t + (jb * 8 + t) * D + half * 32);
#pragma unroll
                for (int c = 0; c < 8; ++c) u[c] = h * wc[c] + u[c];
            }
        }
    }

    __syncthreads();  // all h reads in the block complete before any store

    if (active) {
        const f4* __restrict__ ev = (const f4*)(emb + (size_t)n * D + half * 32);
        f4* __restrict__ ov = (f4*)(io + (size_t)n * D + half * 32);
#pragma unroll
        for (int c = 0; c < 8; ++c) {
            f4 r;
            r[0] = ev[c][0] + fmaxf(u[c][0], 0.0f);
            r[1] = ev[c][1] + fmaxf(u[c][1], 0.0f);
            r[2] = ev[c][2] + fmaxf(u[c][2], 0.0f);
            r[3] = ev[c][3] + fmaxf(u[c][3], 0.0f);
            ov[c] = r;
        }
    }
}

extern "C" void kernel_launch(void* const* d_in, const int* in_sizes, int n_in,
                              void* d_out, int out_size, void* d_ws, size_t ws_size,
                              hipStream_t stream) {
    const void*  edges = d_in[0];
    const float* emb   = (const float*)d_in[1];
    const float* w1    = (const float*)d_in[2];
    const float* b1    = (const float*)d_in[3];
    const float* w2    = (const float*)d_in[4];
    const float* b2    = (const float*)d_in[5];
    float*       out   = (float*)d_out;

    int*   flag = (int*)d_ws;
    float* w2t  = (float*)((char*)d_ws + 256);  // 32 KB transposed w2

    const int E = in_sizes[0] / 2;  // 1,250,000 edges

    // d_out doubles as the messages accumulator: zero it first.
    hipMemsetAsync(out, 0, (size_t)N_NODES * D * sizeof(float), stream);

    detect_kernel<<<1, 256, 0, stream>>>((const unsigned int*)edges, flag);
    transpose_w2_kernel<<<(D * H + 255) / 256, 256, 0, stream>>>(w2, w2t);

    // 32 lanes per edge (float2 each) -> E*32 threads.
    long long sthreads = (long long)E * 32;
    int       sblocks  = (int)((sthreads + 255) / 256);
    scatter_kernel<<<sblocks, 256, 0, stream>>>(edges, emb, out, flag, E);

    int hblocks = (N_NODES + 255) / 256;
    hidden_kernel<<<hblocks, 256, 0, stream>>>(out, w1, b1);

    // 2 threads per node -> 2M threads, 128 nodes per 256-thread block.
    int oblocks = (N_NODES * 2 + 255) / 256;
    out_kernel<<<oblocks, 256, 0, stream>>>(out, emb, w2t, b2);
}